// Round 2
// baseline (504.942 us; speedup 1.0000x reference)
//
#include <hip/hip_runtime.h>
#include <hip/hip_bf16.h>

// out[b,s,o] = x @ w_eff^T + bias, where
//   w_eff[o][k] = r*lut4[o][c4] + (1-r)*lut5[o][c5],  c5 = 2*c4 + b4
//   combined: lut_c[o][c5] = r*lut4[o][c5>>1] + (1-r)*lut5[o][c5]  (one lookup)
//   r = 2 - 3*sigmoid(z).  M=8192, N=4096, K=4096.

#define IN_F   4096
#define OUT_F  4096
#define M_DIM  8192   // 4*2048

#define CAST_BLOCKS 8192   // M*K/(16*256)
#define DEQ_BLOCKS  2048   // OUT_F*(IN_F/32)/256

#define NT (IN_F / 64)     // 64 K-tiles of BK=64
#define TSH (256 * 64)     // shorts per 256x64 tile buffer (32 KB)

typedef __bf16          bf16x8   __attribute__((ext_vector_type(8)));
typedef float           f32x4    __attribute__((ext_vector_type(4)));
typedef unsigned short  ushortx8 __attribute__((ext_vector_type(8)));

__device__ __forceinline__ unsigned short f32_to_bf16(float f) {
    unsigned int u = __builtin_bit_cast(unsigned int, f);
    u += 0x7fffu + ((u >> 16) & 1u);   // RNE (finite values only here)
    return (unsigned short)(u >> 16);
}

__device__ __forceinline__ void async_load16(const void* g, void* l) {
    __builtin_amdgcn_global_load_lds(
        (const __attribute__((address_space(1))) unsigned int*)g,
        (__attribute__((address_space(3))) unsigned int*)l,
        16, 0, 0);
}

// Stage one 128x64 bf16 half-tile: 2 x global_load_lds dwordx4 per thread.
// LDS dest is linear (wave-uniform base + lane*16B); the XOR swizzle is
// pre-applied to the GLOBAL source column (rule #21: swizzle both sides).
__device__ __forceinline__ void stage_half(const unsigned short* g0,
                                           unsigned short* l0) {
    async_load16(g0, l0);
    async_load16(g0 + (size_t)64 * IN_F, l0 + 4096);
}

// ---------------------------------------------------------------------------
// Kernel 1 (fused prologue): blocks [0,CAST_BLOCKS) cast x fp32->bf16,
// blocks [CAST_BLOCKS, CAST_BLOCKS+DEQ_BLOCKS) dequant weights via combined LUT.
// ---------------------------------------------------------------------------
__global__ __launch_bounds__(256) void prologue_kernel(
    const float* __restrict__ x,           // [M_DIM][IN_F] fp32
    const unsigned int* __restrict__ qw,   // [6][OUT_F][IN_F/32]
    const float* __restrict__ lut4,        // [OUT_F][16]
    const float* __restrict__ lut5,        // [OUT_F][32]
    const float* __restrict__ zp,          // scalar
    unsigned short* __restrict__ xb,       // bf16 [M_DIM][IN_F]
    unsigned short* __restrict__ W)        // bf16 [OUT_F][IN_F]
{
    const int tid = threadIdx.x;

    if (blockIdx.x < CAST_BLOCKS) {
        const size_t i = (size_t)blockIdx.x * 4096 + (size_t)tid * 16;
        const f32x4* src = (const f32x4*)(x + i);
        f32x4 a0 = src[0], a1 = src[1], a2 = src[2], a3 = src[3];
        ushortx8 o0, o1;
        #pragma unroll
        for (int e = 0; e < 4; ++e) {
            o0[e]     = f32_to_bf16(a0[e]);
            o0[4 + e] = f32_to_bf16(a1[e]);
            o1[e]     = f32_to_bf16(a2[e]);
            o1[4 + e] = f32_to_bf16(a3[e]);
        }
        ushortx8* dst = (ushortx8*)(xb + i);
        dst[0] = o0;
        dst[1] = o1;
        return;
    }

    __shared__ float sc[2][32];
    const int bid = blockIdx.x - CAST_BLOCKS;
    const int o0 = bid * 2;

    if (tid < 64) {
        const float z   = zp[0];
        const float sig = 1.0f / (1.0f + __expf(-z));
        const float r   = 2.0f - 3.0f * sig;   // r = 1 - (p - 4), p = 3*sig + 3
        const float ri  = 1.0f - r;
        const int row = tid >> 5;
        const int c   = tid & 31;
        sc[row][c] = r * lut4[(o0 + row) * 16 + (c >> 1)]
                   + ri * lut5[(o0 + row) * 32 + c];
    }
    __syncthreads();

    const int gid = bid * 256 + tid;
    const int lo  = (gid >> 7) & 1;

    const int PS = OUT_F * (IN_F / 32);
    const unsigned int q0 = qw[0 * PS + gid];
    const unsigned int q1 = qw[1 * PS + gid];
    const unsigned int q2 = qw[2 * PS + gid];
    const unsigned int q3 = qw[3 * PS + gid];
    const unsigned int q4 = qw[4 * PS + gid];

    unsigned short outv[32];
    #pragma unroll
    for (int i = 0; i < 32; ++i) {
        const unsigned c5 = (((q0 >> i) & 1u) << 4) | (((q1 >> i) & 1u) << 3) |
                            (((q2 >> i) & 1u) << 2) | (((q3 >> i) & 1u) << 1) |
                             ((q4 >> i) & 1u);
        outv[i] = f32_to_bf16(sc[lo][c5]);
    }

    ushortx8* dst = (ushortx8*)(W + (size_t)gid * 32);
    #pragma unroll
    for (int j = 0; j < 4; ++j) {
        ushortx8 v;
        #pragma unroll
        for (int e = 0; e < 8; ++e) v[e] = outv[j * 8 + e];
        dst[j] = v;
    }
}

// ---------------------------------------------------------------------------
// Kernel 2: bf16 GEMM, 256x256 tile, BK=64, 8 waves (2Mx4N), 8-phase schedule
// (T3+T4 counted vmcnt, T2 st-swizzle, T5 setprio). C = A[M][K]*B[N][K]^T + bias.
//
// LDS swizzle: within each 128B row, 16B chunk index c is stored at c^(row&7).
// Staging pre-swizzles the global source column; ds_reads apply the same XOR.
//
// Pipeline: A triple-buffered (sA[3]), B double-buffered (sB[2]) = 160 KiB.
// Tile t reads bufA[t%3], bufB[t&1]. Phase plan per K-tile t:
//   p0: read A(mi0-3,kk0)+B(kk0) [8 rds]; stage A.h0(t+2) -> bufA[(t+2)%3]
//   p1: read A(mi0-3,kk1)+B(kk1) [8 rds]; stage A.h1(t+2)
//   p2: read A(mi4-7,kk0)        [4 rds]; stage B.h0(t+2) -> bufB[t&1] (free after p1)
//   p3: read A(mi4-7,kk1)        [4 rds]; stage B.h1(t+2); s_waitcnt vmcnt(8)
// vmcnt(8) completes exactly tile t+1's 4 half-tiles (A staged at t-1 p0/p1:
// 8 phases of slack; B staged t-1 p2/p3: ~5 phases), leaving A(t+2)+B(t+2)
// (8 loads) in flight across the barrier — never drains to 0 mid-loop.
// Lifetime audit: stage target bufA[(t+2)%3] was last ds_read at t-1 p3,
// drained by its lgkmcnt(0)+barrier before any t p0 stage issues. Reads of
// bufA[t%3] at p0 are covered by t-1 p3's vmcnt completing A(t),B(t).
// ---------------------------------------------------------------------------

#define MFMA_BF16 __builtin_amdgcn_mfma_f32_16x16x32_bf16

__device__ __forceinline__ void tile_step(
    int t,
    const unsigned short* cA, unsigned short* cB, unsigned short* stA,
    int tid,
    const unsigned short* gA0, const unsigned short* gA1,
    const unsigned short* gB0, const unsigned short* gB1,
    int aBase, int bBase, int ck0, int ck1,
    f32x4 (&acc)[8][4])
{
    bf16x8 af[4], bf0[4], bf1[4];
    const bool st = (t + 2 < NT);

    // ---------------- phase 0: mi0-3 x kk0 ----------------
    #pragma unroll
    for (int m = 0; m < 4; ++m)
        af[m] = *(const bf16x8*)(cA + aBase + m * 1024 + ck0);
    #pragma unroll
    for (int n = 0; n < 4; ++n)
        bf0[n] = *(const bf16x8*)(cB + bBase + n * 1024 + ck0);
    if (st) stage_half(gA0 + (size_t)(t + 2) * 64, stA + tid * 8);
    __builtin_amdgcn_s_barrier();
    asm volatile("s_waitcnt lgkmcnt(0)" ::: "memory");
    __builtin_amdgcn_sched_barrier(0);
    __builtin_amdgcn_s_setprio(1);
    #pragma unroll
    for (int m = 0; m < 4; ++m)
        #pragma unroll
        for (int n = 0; n < 4; ++n)
            acc[m][n] = MFMA_BF16(af[m], bf0[n], acc[m][n], 0, 0, 0);
    __builtin_amdgcn_s_setprio(0);
    __builtin_amdgcn_sched_barrier(0);
    __builtin_amdgcn_s_barrier();

    // ---------------- phase 1: mi0-3 x kk1 ----------------
    #pragma unroll
    for (int m = 0; m < 4; ++m)
        af[m] = *(const bf16x8*)(cA + aBase + m * 1024 + ck1);
    #pragma unroll
    for (int n = 0; n < 4; ++n)
        bf1[n] = *(const bf16x8*)(cB + bBase + n * 1024 + ck1);
    if (st) stage_half(gA1 + (size_t)(t + 2) * 64, stA + 8192 + tid * 8);
    __builtin_amdgcn_s_barrier();
    asm volatile("s_waitcnt lgkmcnt(0)" ::: "memory");
    __builtin_amdgcn_sched_barrier(0);
    __builtin_amdgcn_s_setprio(1);
    #pragma unroll
    for (int m = 0; m < 4; ++m)
        #pragma unroll
        for (int n = 0; n < 4; ++n)
            acc[m][n] = MFMA_BF16(af[m], bf1[n], acc[m][n], 0, 0, 0);
    __builtin_amdgcn_s_setprio(0);
    __builtin_amdgcn_sched_barrier(0);
    __builtin_amdgcn_s_barrier();

    // ---------------- phase 2: mi4-7 x kk0 ----------------
    #pragma unroll
    for (int m = 0; m < 4; ++m)
        af[m] = *(const bf16x8*)(cA + aBase + (m + 4) * 1024 + ck0);
    if (st) stage_half(gB0 + (size_t)(t + 2) * 64, cB + tid * 8);
    __builtin_amdgcn_s_barrier();
    asm volatile("s_waitcnt lgkmcnt(0)" ::: "memory");
    __builtin_amdgcn_sched_barrier(0);
    __builtin_amdgcn_s_setprio(1);
    #pragma unroll
    for (int m = 0; m < 4; ++m)
        #pragma unroll
        for (int n = 0; n < 4; ++n)
            acc[m + 4][n] = MFMA_BF16(af[m], bf0[n], acc[m + 4][n], 0, 0, 0);
    __builtin_amdgcn_s_setprio(0);
    __builtin_amdgcn_sched_barrier(0);
    __builtin_amdgcn_s_barrier();

    // ---------------- phase 3: mi4-7 x kk1 ----------------
    #pragma unroll
    for (int m = 0; m < 4; ++m)
        af[m] = *(const bf16x8*)(cA + aBase + (m + 4) * 1024 + ck1);
    if (st) stage_half(gB1 + (size_t)(t + 2) * 64, cB + 8192 + tid * 8);
    if (t < NT - 2) asm volatile("s_waitcnt vmcnt(8)" ::: "memory");
    else            asm volatile("s_waitcnt vmcnt(0)" ::: "memory");
    __builtin_amdgcn_s_barrier();
    asm volatile("s_waitcnt lgkmcnt(0)" ::: "memory");
    __builtin_amdgcn_sched_barrier(0);
    __builtin_amdgcn_s_setprio(1);
    #pragma unroll
    for (int m = 0; m < 4; ++m)
        #pragma unroll
        for (int n = 0; n < 4; ++n)
            acc[m + 4][n] = MFMA_BF16(af[m], bf1[n], acc[m + 4][n], 0, 0, 0);
    __builtin_amdgcn_s_setprio(0);
    __builtin_amdgcn_sched_barrier(0);
    __builtin_amdgcn_s_barrier();
}

__global__ __launch_bounds__(512, 1) void gemm_bt_kernel(
    const unsigned short* __restrict__ A,   // bf16 [M_DIM][IN_F]
    const unsigned short* __restrict__ B,   // bf16 [OUT_F][IN_F]
    const float* __restrict__ bias,         // [OUT_F]
    float* __restrict__ C)                  // [M_DIM][OUT_F]
{
    __shared__ unsigned short sA[3][TSH];   // 3 x 32 KB (A triple buffer)
    __shared__ unsigned short sB[2][TSH];   // 2 x 32 KB (B double buffer) = 160 KiB

    const int tid = threadIdx.x;

    // XCD-aware bijective swizzle (512 % 8 == 0): each XCD gets 4 bm-rows.
    const int id  = blockIdx.x;
    const int swz = (id & 7) * 64 + (id >> 3);
    const int bn  = swz & 15;   // 0..15  N tiles
    const int bm  = swz >> 4;   // 0..31  M tiles

    const int l   = tid & 63;
    const int wv  = tid >> 6;   // 0..7
    const int wr  = wv >> 2;    // 0..1  (M half)
    const int wc  = wv & 3;     // 0..3  (N quarter)
    const int l15 = l & 15;
    const int q   = l >> 4;
    const int xm  = l15 & 7;

    // ds_read bases (shorts). Fragment (row, 16B-chunk c) lives at c^(row&7).
    const int aBase = (wr * 128 + l15) * 64;
    const int bBase = (wc * 64  + l15) * 64;
    const int ck0   = ((q)     ^ xm) * 8;
    const int ck1   = ((4 + q) ^ xm) * 8;

    // staging addressing: thread -> (row r, pre-swizzled chunk) of a half-tile
    const int r  = tid >> 3;                     // 0..63
    const int cx = ((tid & 7) ^ (r & 7)) * 8;    // element offset in BK
    const unsigned short* gA0 = A + (size_t)(bm * 256 + r) * IN_F + cx;
    const unsigned short* gA1 = gA0 + (size_t)128 * IN_F;
    const unsigned short* gB0 = B + (size_t)(bn * 256 + r) * IN_F + cx;
    const unsigned short* gB1 = gB0 + (size_t)128 * IN_F;

    // Pipeline prologue: stage A0,B0,A1,B1 (16 loads); vmcnt(8) completes
    // A0,B0 — A1,B1 stay in flight (steady-state invariant from tile 0 on).
    stage_half(gA0,      &sA[0][0] + tid * 8);
    stage_half(gA1,      &sA[0][0] + 8192 + tid * 8);
    stage_half(gB0,      &sB[0][0] + tid * 8);
    stage_half(gB1,      &sB[0][0] + 8192 + tid * 8);
    stage_half(gA0 + 64, &sA[1][0] + tid * 8);
    stage_half(gA1 + 64, &sA[1][0] + 8192 + tid * 8);
    stage_half(gB0 + 64, &sB[1][0] + tid * 8);
    stage_half(gB1 + 64, &sB[1][0] + 8192 + tid * 8);
    asm volatile("s_waitcnt vmcnt(8)" ::: "memory");
    __builtin_amdgcn_s_barrier();

    f32x4 acc[8][4] = {};

    int ai = 0, bi = 0;
    #pragma unroll 1
    for (int t = 0; t < NT; ++t) {
        int a2 = ai + 2; if (a2 >= 3) a2 -= 3;   // stage target: bufA[(t+2)%3]
        tile_step(t, &sA[ai][0], &sB[bi][0], &sA[a2][0], tid,
                  gA0, gA1, gB0, gB1, aBase, bBase, ck0, ck1, acc);
        ai = (ai == 2) ? 0 : ai + 1;
        bi ^= 1;
    }

    // Epilogue: C/D layout col = lane&15, row = (lane>>4)*4 + reg  [m89-verified]
    const int row0 = bm * 256 + wr * 128 + q * 4;
    const int col0 = bn * 256 + wc * 64 + l15;
    #pragma unroll
    for (int n = 0; n < 4; ++n) {
        const float bv = bias[col0 + n * 16];
        #pragma unroll
        for (int m = 0; m < 8; ++m) {
            #pragma unroll
            for (int rr = 0; rr < 4; ++rr)
                C[(size_t)(row0 + m * 16 + rr) * OUT_F + (col0 + n * 16)] =
                    acc[m][n][rr] + bv;
        }
    }
}

extern "C" void kernel_launch(void* const* d_in, const int* in_sizes, int n_in,
                              void* d_out, int out_size, void* d_ws, size_t ws_size,
                              hipStream_t stream)
{
    const float*        x    = (const float*)d_in[0];        // (4,2048,4096)
    const float*        z    = (const float*)d_in[1];        // scalar
    const float*        lut4 = (const float*)d_in[2];        // (4096,16)
    const float*        lut5 = (const float*)d_in[3];        // (4096,32)
    const float*        bias = (const float*)d_in[4];        // (4096,)
    const unsigned int* qw   = (const unsigned int*)d_in[5]; // (6,4096,128)
    float* out = (float*)d_out;                              // (4,2048,4096)

    unsigned short* xb = (unsigned short*)d_ws;              // bf16, 64 MB
    unsigned short* wb = xb + (size_t)M_DIM * IN_F;          // bf16, 32 MB

    prologue_kernel<<<CAST_BLOCKS + DEQ_BLOCKS, 256, 0, stream>>>(
        x, qw, lut4, lut5, z, xb, wb);
    gemm_bt_kernel<<<(M_DIM / 256) * (OUT_F / 256), 512, 0, stream>>>(
        xb, wb, bias, out);
}

// Round 3
// 467.753 us; speedup vs baseline: 1.0795x; 1.0795x over previous
//
#include <hip/hip_runtime.h>
#include <hip/hip_bf16.h>

// out[b,s,o] = x @ w_eff^T + bias, where
//   w_eff[o][k] = r*lut4[o][c4] + (1-r)*lut5[o][c5],  c5 = 2*c4 + b4
//   combined: lut_c[o][c5] = r*lut4[o][c5>>1] + (1-r)*lut5[o][c5]  (one lookup)
//   r = 2 - 3*sigmoid(z).  M=8192, N=4096, K=4096.

#define IN_F   4096
#define OUT_F  4096
#define M_DIM  8192   // 4*2048

#define CAST_BLOCKS 8192   // M*K/(16*256)
#define DEQ_BLOCKS  2048   // OUT_F*(IN_F/32)/256

#define NT (IN_F / 64)     // 64 K-tiles of BK=64
#define TSH (256 * 64)     // shorts per 256x64 tile buffer (32 KB)

typedef __bf16          bf16x8   __attribute__((ext_vector_type(8)));
typedef float           f32x4    __attribute__((ext_vector_type(4)));
typedef unsigned short  ushortx8 __attribute__((ext_vector_type(8)));

__device__ __forceinline__ unsigned short f32_to_bf16(float f) {
    unsigned int u = __builtin_bit_cast(unsigned int, f);
    u += 0x7fffu + ((u >> 16) & 1u);   // RNE (finite values only here)
    return (unsigned short)(u >> 16);
}

__device__ __forceinline__ void async_load16(const void* g, void* l) {
    __builtin_amdgcn_global_load_lds(
        (const __attribute__((address_space(1))) unsigned int*)g,
        (__attribute__((address_space(3))) unsigned int*)l,
        16, 0, 0);
}

// Stage one 128x64 bf16 half-tile: 2 x global_load_lds dwordx4 per thread.
// LDS dest is linear (wave-uniform base + lane*16B); the XOR swizzle is
// pre-applied to the GLOBAL source column (rule #21: swizzle both sides).
__device__ __forceinline__ void stage_half(const unsigned short* g0,
                                           unsigned short* l0) {
    async_load16(g0, l0);
    async_load16(g0 + (size_t)64 * IN_F, l0 + 4096);
}

// ---------------------------------------------------------------------------
// Kernel 1 (fused prologue): blocks [0,CAST_BLOCKS) cast x fp32->bf16,
// blocks [CAST_BLOCKS, CAST_BLOCKS+DEQ_BLOCKS) dequant weights via combined LUT.
// ---------------------------------------------------------------------------
__global__ __launch_bounds__(256) void prologue_kernel(
    const float* __restrict__ x,           // [M_DIM][IN_F] fp32
    const unsigned int* __restrict__ qw,   // [6][OUT_F][IN_F/32]
    const float* __restrict__ lut4,        // [OUT_F][16]
    const float* __restrict__ lut5,        // [OUT_F][32]
    const float* __restrict__ zp,          // scalar
    unsigned short* __restrict__ xb,       // bf16 [M_DIM][IN_F]
    unsigned short* __restrict__ W)        // bf16 [OUT_F][IN_F]
{
    const int tid = threadIdx.x;

    if (blockIdx.x < CAST_BLOCKS) {
        const size_t i = (size_t)blockIdx.x * 4096 + (size_t)tid * 16;
        const f32x4* src = (const f32x4*)(x + i);
        f32x4 a0 = src[0], a1 = src[1], a2 = src[2], a3 = src[3];
        ushortx8 o0, o1;
        #pragma unroll
        for (int e = 0; e < 4; ++e) {
            o0[e]     = f32_to_bf16(a0[e]);
            o0[4 + e] = f32_to_bf16(a1[e]);
            o1[e]     = f32_to_bf16(a2[e]);
            o1[4 + e] = f32_to_bf16(a3[e]);
        }
        ushortx8* dst = (ushortx8*)(xb + i);
        dst[0] = o0;
        dst[1] = o1;
        return;
    }

    __shared__ float sc[2][32];
    const int bid = blockIdx.x - CAST_BLOCKS;
    const int o0 = bid * 2;

    if (tid < 64) {
        const float z   = zp[0];
        const float sig = 1.0f / (1.0f + __expf(-z));
        const float r   = 2.0f - 3.0f * sig;   // r = 1 - (p - 4), p = 3*sig + 3
        const float ri  = 1.0f - r;
        const int row = tid >> 5;
        const int c   = tid & 31;
        sc[row][c] = r * lut4[(o0 + row) * 16 + (c >> 1)]
                   + ri * lut5[(o0 + row) * 32 + c];
    }
    __syncthreads();

    const int gid = bid * 256 + tid;
    const int lo  = (gid >> 7) & 1;

    const int PS = OUT_F * (IN_F / 32);
    const unsigned int q0 = qw[0 * PS + gid];
    const unsigned int q1 = qw[1 * PS + gid];
    const unsigned int q2 = qw[2 * PS + gid];
    const unsigned int q3 = qw[3 * PS + gid];
    const unsigned int q4 = qw[4 * PS + gid];

    unsigned short outv[32];
    #pragma unroll
    for (int i = 0; i < 32; ++i) {
        const unsigned c5 = (((q0 >> i) & 1u) << 4) | (((q1 >> i) & 1u) << 3) |
                            (((q2 >> i) & 1u) << 2) | (((q3 >> i) & 1u) << 1) |
                             ((q4 >> i) & 1u);
        outv[i] = f32_to_bf16(sc[lo][c5]);
    }

    ushortx8* dst = (ushortx8*)(W + (size_t)gid * 32);
    #pragma unroll
    for (int j = 0; j < 4; ++j) {
        ushortx8 v;
        #pragma unroll
        for (int e = 0; e < 8; ++e) v[e] = outv[j * 8 + e];
        dst[j] = v;
    }
}

// ---------------------------------------------------------------------------
// Kernel 2: bf16 GEMM, 256x256 tile, BK=64, 8 waves (2Mx4N), double-buffered
// LDS (128 KiB), counted vmcnt, XOR st-swizzle, setprio. 2 barriers per K-tile.
//
// LDS swizzle: within each 128B row, 16B chunk index c is stored at c^(row&7).
// Staging pre-swizzles the global source column; ds_reads apply the same XOR.
//
// Per K-tile t (cA=sA[t&1], cB=sB[t&1], nA=sA[(t+1)&1]):
//   half 1: read bf0,bf1 (B kk0,kk1) + A m0-3; stage A(t+1)->nA;
//           MFMA acc[0..3] over kk0,kk1.          [no intra barriers: waves
//           de-lockstep, one wave's ds_reads overlap the other's MFMAs]
//   -- barrier (all B LDS reads of this tile complete; B-stage now safe) --
//   half 2: read A m4-7; stage B(t+2)->cB (B(t) fully in regs);
//           MFMA acc[4..7] over kk0,kk1.
//   -- vmcnt(4) + barrier (completes A(t+1),B(t+1); leaves B(t+2) in flight) --
//
// vmcnt audit (per-wave, 4 stage ops/tile-half): steady state at boundary:
// outstanding = B(t+1)[4, oldest] + A(t+1)[4] + B(t+2)[4] = 12; vmcnt(4)
// completes B(t+1)+A(t+1) — exactly what tile t+1 reads — never drains to 0.
// Prologue stages A0,B0,B1 (12 ops); vmcnt(4) leaves B1: same invariant.
// Hazards: A-stage->nA after boundary barrier (nA's readers all pre-barrier);
// B-stage->cB after mid barrier (cB's readers all pre-barrier); sched_barrier(0)
// fences hug each raw s_barrier so no ds_read is hoisted across.
// ---------------------------------------------------------------------------

#define MFMA_BF16 __builtin_amdgcn_mfma_f32_16x16x32_bf16

__device__ __forceinline__ void tile_step(
    int t,
    const unsigned short* cA, unsigned short* cB, unsigned short* nA,
    int tid,
    const unsigned short* gA0, const unsigned short* gA1,
    const unsigned short* gB0, const unsigned short* gB1,
    int aBase, int bBase, int ck0, int ck1,
    f32x4 (&acc)[8][4])
{
    bf16x8 bf0[4], bf1[4], afa[4], afb[4], afc[4], afd[4];

    // ---------------- half 1: m0-3, kk0+kk1 ----------------
    #pragma unroll
    for (int n = 0; n < 4; ++n)
        bf0[n] = *(const bf16x8*)(cB + bBase + n * 1024 + ck0);
    #pragma unroll
    for (int n = 0; n < 4; ++n)
        bf1[n] = *(const bf16x8*)(cB + bBase + n * 1024 + ck1);
    #pragma unroll
    for (int m = 0; m < 4; ++m)
        afa[m] = *(const bf16x8*)(cA + aBase + m * 1024 + ck0);

    if (t + 1 < NT) {
        stage_half(gA0 + (size_t)(t + 1) * 64, nA + tid * 8);
        stage_half(gA1 + (size_t)(t + 1) * 64, nA + 8192 + tid * 8);
    }

    __builtin_amdgcn_s_setprio(1);
    #pragma unroll
    for (int m = 0; m < 4; ++m)
        #pragma unroll
        for (int n = 0; n < 4; ++n)
            acc[m][n] = MFMA_BF16(afa[m], bf0[n], acc[m][n], 0, 0, 0);
    __builtin_amdgcn_s_setprio(0);

    #pragma unroll
    for (int m = 0; m < 4; ++m)
        afb[m] = *(const bf16x8*)(cA + aBase + m * 1024 + ck1);

    __builtin_amdgcn_s_setprio(1);
    #pragma unroll
    for (int m = 0; m < 4; ++m)
        #pragma unroll
        for (int n = 0; n < 4; ++n)
            acc[m][n] = MFMA_BF16(afb[m], bf1[n], acc[m][n], 0, 0, 0);
    __builtin_amdgcn_s_setprio(0);

    // ---- mid-tile barrier: all waves done with B LDS reads ----
    __builtin_amdgcn_sched_barrier(0);
    __builtin_amdgcn_s_barrier();
    __builtin_amdgcn_sched_barrier(0);

    // ---------------- half 2: m4-7, kk0+kk1 ----------------
    #pragma unroll
    for (int m = 0; m < 4; ++m)
        afc[m] = *(const bf16x8*)(cA + aBase + (m + 4) * 1024 + ck0);

    if (t + 2 < NT) {
        stage_half(gB0 + (size_t)(t + 2) * 64, cB + tid * 8);
        stage_half(gB1 + (size_t)(t + 2) * 64, cB + 8192 + tid * 8);
    }

    __builtin_amdgcn_s_setprio(1);
    #pragma unroll
    for (int m = 0; m < 4; ++m)
        #pragma unroll
        for (int n = 0; n < 4; ++n)
            acc[m + 4][n] = MFMA_BF16(afc[m], bf0[n], acc[m + 4][n], 0, 0, 0);
    __builtin_amdgcn_s_setprio(0);

    #pragma unroll
    for (int m = 0; m < 4; ++m)
        afd[m] = *(const bf16x8*)(cA + aBase + (m + 4) * 1024 + ck1);

    __builtin_amdgcn_s_setprio(1);
    #pragma unroll
    for (int m = 0; m < 4; ++m)
        #pragma unroll
        for (int n = 0; n < 4; ++n)
            acc[m + 4][n] = MFMA_BF16(afd[m], bf1[n], acc[m + 4][n], 0, 0, 0);
    __builtin_amdgcn_s_setprio(0);

    // ---- boundary: counted vmcnt + barrier ----
    __builtin_amdgcn_sched_barrier(0);
    if (t < NT - 2) asm volatile("s_waitcnt vmcnt(4)" ::: "memory");
    else            asm volatile("s_waitcnt vmcnt(0)" ::: "memory");
    __builtin_amdgcn_s_barrier();
    __builtin_amdgcn_sched_barrier(0);
}

__global__ __launch_bounds__(512, 2) void gemm_bt_kernel(
    const unsigned short* __restrict__ A,   // bf16 [M_DIM][IN_F]
    const unsigned short* __restrict__ B,   // bf16 [OUT_F][IN_F]
    const float* __restrict__ bias,         // [OUT_F]
    float* __restrict__ C)                  // [M_DIM][OUT_F]
{
    __shared__ unsigned short sA[2][TSH];   // 2 x 32 KB
    __shared__ unsigned short sB[2][TSH];   // 2 x 32 KB  (128 KiB total)

    const int tid = threadIdx.x;

    // XCD-aware bijective swizzle (512 % 8 == 0): each XCD gets 4 bm-rows.
    const int id  = blockIdx.x;
    const int swz = (id & 7) * 64 + (id >> 3);
    const int bn  = swz & 15;   // 0..15  N tiles
    const int bm  = swz >> 4;   // 0..31  M tiles

    const int l   = tid & 63;
    const int wv  = tid >> 6;   // 0..7
    const int wr  = wv >> 2;    // 0..1  (M half)
    const int wc  = wv & 3;     // 0..3  (N quarter)
    const int l15 = l & 15;
    const int q   = l >> 4;
    const int xm  = l15 & 7;

    // ds_read bases (shorts). Fragment (row, 16B-chunk c) lives at c^(row&7).
    const int aBase = (wr * 128 + l15) * 64;
    const int bBase = (wc * 64  + l15) * 64;
    const int ck0   = ((q)     ^ xm) * 8;
    const int ck1   = ((4 + q) ^ xm) * 8;

    // staging addressing: thread -> (row r, pre-swizzled chunk) of a half-tile
    const int r  = tid >> 3;                     // 0..63
    const int cx = ((tid & 7) ^ (r & 7)) * 8;    // element offset in BK
    const unsigned short* gA0 = A + (size_t)(bm * 256 + r) * IN_F + cx;
    const unsigned short* gA1 = gA0 + (size_t)128 * IN_F;
    const unsigned short* gB0 = B + (size_t)(bn * 256 + r) * IN_F + cx;
    const unsigned short* gB1 = gB0 + (size_t)128 * IN_F;

    // Prologue: stage A(0), B(0), B(1) (12 ops); vmcnt(4) completes A0,B0 —
    // B(1) stays in flight (steady-state invariant from tile 0 on).
    stage_half(gA0,      &sA[0][0] + tid * 8);
    stage_half(gA1,      &sA[0][0] + 8192 + tid * 8);
    stage_half(gB0,      &sB[0][0] + tid * 8);
    stage_half(gB1,      &sB[0][0] + 8192 + tid * 8);
    stage_half(gB0 + 64, &sB[1][0] + tid * 8);
    stage_half(gB1 + 64, &sB[1][0] + 8192 + tid * 8);
    asm volatile("s_waitcnt vmcnt(4)" ::: "memory");
    __builtin_amdgcn_s_barrier();
    __builtin_amdgcn_sched_barrier(0);

    f32x4 acc[8][4] = {};

    #pragma unroll 1
    for (int tp = 0; tp < NT; tp += 2) {
        tile_step(tp,     &sA[0][0], &sB[0][0], &sA[1][0], tid,
                  gA0, gA1, gB0, gB1, aBase, bBase, ck0, ck1, acc);
        tile_step(tp + 1, &sA[1][0], &sB[1][0], &sA[0][0], tid,
                  gA0, gA1, gB0, gB1, aBase, bBase, ck0, ck1, acc);
    }

    // Epilogue: C/D layout col = lane&15, row = (lane>>4)*4 + reg  [m89-verified]
    const int row0 = bm * 256 + wr * 128 + q * 4;
    const int col0 = bn * 256 + wc * 64 + l15;
    #pragma unroll
    for (int n = 0; n < 4; ++n) {
        const float bv = bias[col0 + n * 16];
        #pragma unroll
        for (int m = 0; m < 8; ++m) {
            #pragma unroll
            for (int rr = 0; rr < 4; ++rr)
                C[(size_t)(row0 + m * 16 + rr) * OUT_F + (col0 + n * 16)] =
                    acc[m][n][rr] + bv;
        }
    }
}

extern "C" void kernel_launch(void* const* d_in, const int* in_sizes, int n_in,
                              void* d_out, int out_size, void* d_ws, size_t ws_size,
                              hipStream_t stream)
{
    const float*        x    = (const float*)d_in[0];        // (4,2048,4096)
    const float*        z    = (const float*)d_in[1];        // scalar
    const float*        lut4 = (const float*)d_in[2];        // (4096,16)
    const float*        lut5 = (const float*)d_in[3];        // (4096,32)
    const float*        bias = (const float*)d_in[4];        // (4096,)
    const unsigned int* qw   = (const unsigned int*)d_in[5]; // (6,4096,128)
    float* out = (float*)d_out;                              // (4,2048,4096)

    unsigned short* xb = (unsigned short*)d_ws;              // bf16, 64 MB
    unsigned short* wb = xb + (size_t)M_DIM * IN_F;          // bf16, 32 MB

    prologue_kernel<<<CAST_BLOCKS + DEQ_BLOCKS, 256, 0, stream>>>(
        x, qw, lut4, lut5, z, xb, wb);
    gemm_bt_kernel<<<(M_DIM / 256) * (OUT_F / 256), 512, 0, stream>>>(
        xb, wb, bias, out);
}